// Round 16
// baseline (77.634 us; speedup 1.0000x reference)
//
#include <hip/hip_runtime.h>

typedef _Float16 half8 __attribute__((ext_vector_type(8)));
typedef float f32x4 __attribute__((ext_vector_type(4)));

#define MFMA16(a, b, c) __builtin_amdgcn_mfma_f32_16x16x32_f16((a), (b), (c), 0, 0, 0)

static __device__ __forceinline__ unsigned short hfbits(float f) {
  return __builtin_bit_cast(unsigned short, (_Float16)f);
}

// async global->LDS, 16B per lane; LDS dest = uniform base + lane*16
static __device__ __forceinline__ void gl16(const ushort* g, ushort* l) {
  __builtin_amdgcn_global_load_lds(
      (const __attribute__((address_space(1))) unsigned int*)g,
      (__attribute__((address_space(3))) unsigned int*)l, 16, 0, 0);
}

// ---------------------------------------------------------------------------
// Kernel 1 (merged prep): blocks [0,768): W f32 -> Wt fp16 transposed;
// blocks [768,2816): x f32 -> xh fp16.  Block 768 additionally runs a
// block-wide prefix scan of mask per batch, producing:
//   cidx[b][jc]   = j-index of the jc-th surviving key (pads -> 0)
//   biasc[b][jc]  = 0 for jc < nkv[b], -1e9 for pads (QK C-init masking)
//   nkvs[b]=nkv, nkvs[2+b]=ceil64(nkv)
// ---------------------------------------------------------------------------
__global__ __launch_bounds__(256) void k_prep(const float* __restrict__ W,
                                              ushort* __restrict__ wt,
                                              const float* __restrict__ x,
                                              ushort* __restrict__ xh,
                                              const int* __restrict__ mask,
                                              float* __restrict__ biasc,
                                              int* __restrict__ cidx,
                                              int* __restrict__ nkvs) {
  __shared__ ushort tile[64][72];
  __shared__ int scnt[256];
  const int id = blockIdx.x;
  const int t = threadIdx.x;

  if (id >= 768) {                       // ---- xh cast part
    const int pb = id - 768;
    const size_t p = ((size_t)pb * 256 + t) * 8;
    float4 a = *reinterpret_cast<const float4*>(x + p);
    float4 b = *reinterpret_cast<const float4*>(x + p + 4);
    union { ushort u[8]; uint4 v; } pk;
    pk.u[0] = hfbits(a.x); pk.u[1] = hfbits(a.y);
    pk.u[2] = hfbits(a.z); pk.u[3] = hfbits(a.w);
    pk.u[4] = hfbits(b.x); pk.u[5] = hfbits(b.y);
    pk.u[6] = hfbits(b.z); pk.u[7] = hfbits(b.w);
    *reinterpret_cast<uint4*>(xh + p) = pk.v;

    if (pb == 0) {                       // ---- key-compaction scan
      for (int b = 0; b < 2; ++b) {
        const int* mb = mask + b * 2048;
        int mloc[8];
        int c = 0;
#pragma unroll
        for (int k = 0; k < 8; ++k) {
          mloc[k] = mb[t * 8 + k];
          c += (mloc[k] != 0);
        }
        scnt[t] = c;
        __syncthreads();
        // inclusive Hillis-Steele scan over 256 counts
        for (int off = 1; off < 256; off <<= 1) {
          int v = scnt[t];
          int u = (t >= off) ? scnt[t - off] : 0;
          __syncthreads();
          scnt[t] = v + u;
          __syncthreads();
        }
        const int total = scnt[255];
        int p2 = scnt[t] - c;            // exclusive prefix
#pragma unroll
        for (int k = 0; k < 8; ++k)
          if (mloc[k]) cidx[b * 2048 + (p2++)] = t * 8 + k;
        __syncthreads();
        for (int jc = t; jc < 2048; jc += 256) {
          if (jc >= total) cidx[b * 2048 + jc] = 0;   // pad -> valid row 0
          biasc[b * 2048 + jc] = (jc < total) ? 0.f : -1e9f;
        }
        if (t == 0) {
          nkvs[b] = total;
          nkvs[2 + b] = ((total + 63) >> 6) << 6;
        }
        __syncthreads();
      }
    }
    return;
  }

  // ---- Wt transpose part
  const int n0 = (id % 48) * 64, k0 = (id / 48) * 64;
#pragma unroll
  for (int i = 0; i < 4; ++i) {
    int p = t + i * 256;
    int r = p >> 4, c = (p & 15) << 2;
    float4 v = *reinterpret_cast<const float4*>(&W[(size_t)(k0 + r) * 3072 + n0 + c]);
    ushort4 u;
    u.x = hfbits(v.x); u.y = hfbits(v.y); u.z = hfbits(v.z); u.w = hfbits(v.w);
    *reinterpret_cast<ushort4*>(&tile[r][c]) = u;
  }
  __syncthreads();
#pragma unroll
  for (int i = 0; i < 4; ++i) {
    int p = t + i * 256;
    int rn = p >> 4, ck = (p & 15) << 2;
    ushort4 u;
    u.x = tile[ck + 0][rn]; u.y = tile[ck + 1][rn];
    u.z = tile[ck + 2][rn]; u.w = tile[ck + 3][rn];
    *reinterpret_cast<ushort4*>(&wt[(size_t)(n0 + rn) * 1024 + k0 + ck]) = u;
  }
}

// ---------------------------------------------------------------------------
// Kernel 2: qkv GEMM, 64x64 tiles.  R15 proved cross-block TLP is the
// binding resource: 48KB LDS capped residency at 3 blocks/CU.  64x64 tiles
// give 32KB LDS -> 5 resident blocks/CU = 20 waves/CU and ~2080 active
// blocks (8.1/CU launched).  Per wave: 16x64 output (acc[4]), 8 MFMA +
// 4 gl16/iter, counted wait vmcnt(4).  2-phase dbuf + XCD chunking kept.
// ---------------------------------------------------------------------------
__global__ __launch_bounds__(256) void k_gemm(const ushort* __restrict__ xh,
                                              const ushort* __restrict__ wt,
                                              ushort* __restrict__ qw,
                                              ushort* __restrict__ kw,
                                              ushort* __restrict__ vc,
                                              const int* __restrict__ cidx,
                                              const int* __restrict__ nkvs) {
  __shared__ __align__(16) ushort sA[2][64 * 64];    // 16 KB (2 bufs)
  __shared__ __align__(16) ushort sB[2][64 * 64];    // 16 KB (2 bufs)
  const int t = threadIdx.x;
  const int lane = t & 63, w = t >> 6;
  const int g = lane >> 4, lr = lane & 15;

  const int id = blockIdx.x;
  int ncol0, batch = 0, mrow0 = 0;     // ncol0: global N col base (of 3072)
  int which, h;
  bool compact = false;
  if (id < 1024) {
    // Q part, XCD-chunked: per XCD an 8bn x 16bm chunk
    const int xcd = id & 7, wi = id >> 3;        // wi 0..127
    const int bn = (xcd & 1) * 8 + (wi & 7);     // head 0..15
    mrow0 = ((xcd >> 1) * 16 + (wi >> 3)) * 64;  // bm 0..63
    ncol0 = bn * 64;
    which = 0; h = bn;
  } else {
    // KV part, XCD-chunked; bmc interleaved across XCDs for even early-exit
    const int kid = id - 1024;                   // 0..2047
    const int xcd = kid & 7, wi = kid >> 3;      // wi 0..255
    const int col = (xcd & 1) * 16 + (wi & 15);  // 0..31
    const int bmc = (wi >> 4) * 4 + (xcd >> 1);  // 0..63
    const int mt0 = (nkvs[0] + 63) >> 6;
    const int mt1 = (nkvs[1] + 63) >> 6;
    if (bmc < mt0) { batch = 0; mrow0 = bmc * 64; }
    else if (bmc < mt0 + mt1) { batch = 1; mrow0 = (bmc - mt0) * 64; }
    else return;                        // no surviving rows here
    compact = true;
    ncol0 = 1024 + col * 64;
    which = (col < 16) ? 1 : 2;
    h = col & 15;
  }

  // ---- A staging: 8 chunks (1KB); wave w stages chunks 2w..2w+1.
  int soffA[2];
  const ushort* asrc[2];
#pragma unroll
  for (int i = 0; i < 2; ++i) {
    const int c = 2 * w + i;
    const int r = c * 8 + (lane >> 3);
    const int sl = (lane & 7) ^ (((r & 3) << 1) ^ ((r >> 3) & 3));
    soffA[i] = sl * 8;
    int arow;
    if (compact) arow = batch * 2048 + cidx[batch * 2048 + mrow0 + r];
    else arow = mrow0 + r;
    asrc[i] = xh + (size_t)arow * 1024 + soffA[i];
  }
  // ---- B staging: 8 chunks; wave w stages chunks 2w..2w+1.
  int brow[2], soffB[2];
#pragma unroll
  for (int i = 0; i < 2; ++i) {
    const int c = 2 * w + i;
    const int r = c * 8 + (lane >> 3);
    const int sl = (lane & 7) ^ (((r & 3) << 1) ^ ((r >> 3) & 3));
    brow[i] = r;
    soffB[i] = sl * 8;
  }

  // read-side swizzles
  const int ra = w * 16 + lr;
  const int raswz = ((((ra & 3) << 1) ^ ((ra >> 3) & 3)) << 4);
  int rbswz[4];
#pragma unroll
  for (int cs = 0; cs < 4; ++cs) {
    const int rb = cs * 16 + lr;
    rbswz[cs] = ((((rb & 3) << 1) ^ ((rb >> 3) & 3)) << 4);
  }

  auto stage = [&](int bi, int kt) {
#pragma unroll
    for (int i = 0; i < 2; ++i) {
      gl16(asrc[i] + kt, sA[bi] + (2 * w + i) * 512);
      gl16(wt + (size_t)(ncol0 + brow[i]) * 1024 + kt + soffB[i],
           sB[bi] + (2 * w + i) * 512);
    }
  };

  f32x4 acc[4] = {};

  stage(0, 0);
  for (int it = 0; it < 16; ++it) {
    if (it < 15) {
      stage((it + 1) & 1, (it + 1) * 64);
      asm volatile("s_waitcnt vmcnt(4)" ::: "memory");   // prev stage landed
    } else {
      asm volatile("s_waitcnt vmcnt(0)" ::: "memory");
    }
    __builtin_amdgcn_sched_barrier(0);
    __builtin_amdgcn_s_barrier();
    __builtin_amdgcn_sched_barrier(0);

    const int cb = it & 1;
#pragma unroll
    for (int ks = 0; ks < 64; ks += 32) {
      half8 af, bb[4];
      af = *reinterpret_cast<const half8*>(
          (const char*)sA[cb] + ra * 128 + ((16 * g + 2 * ks) ^ raswz));
#pragma unroll
      for (int cs = 0; cs < 4; ++cs) {
        const int rb = cs * 16 + lr;
        bb[cs] = *reinterpret_cast<const half8*>(
            (const char*)sB[cb] + rb * 128 + ((16 * g + 2 * ks) ^ rbswz[cs]));
      }
#pragma unroll
      for (int cs = 0; cs < 4; ++cs)
        acc[cs] = MFMA16(af, bb[cs], acc[cs]);
    }
    __builtin_amdgcn_sched_barrier(0);
    __builtin_amdgcn_s_barrier();      // readers done before buf overwrite
    __builtin_amdgcn_sched_barrier(0);
  }

  const int m0 = mrow0 + w * 16;        // wave's row base (Q: global, KV: jc)

  if (which == 2) {
    // ---- V: per-wave 16x64 LDS transpose -> vc[bh][d][jc] (compacted).
    // Own-wave 2KB quadrant in sA[0] (all waves past final barrier).
    ushort* q = sA[0] + w * 1024;       // 16 jc x 64 d, row n stride 16
#pragma unroll
    for (int r = 0; r < 4; ++r) {
      const int ml = g * 4 + r;                    // local jc 0..15
#pragma unroll
      for (int cs = 0; cs < 4; ++cs) {
        const int n = cs * 16 + lr;                // d 0..63
        q[n * 16 + ((((ml >> 3) ^ (n & 1)) << 3) | (ml & 7))] =
            hfbits(acc[cs][r]);
      }
    }
    ushort* vbase = vc + ((size_t)((batch << 4) + h) * 64) * 2048 + m0;
#pragma unroll
    for (int mg = 0; mg < 2; ++mg) {
      const int dl = lane;                         // d 0..63
      uint4 vv = *reinterpret_cast<const uint4*>(
          q + dl * 16 + ((mg ^ (dl & 1)) << 3));
      *reinterpret_cast<uint4*>(vbase + (size_t)dl * 2048 + mg * 8) = vv;
    }
  } else if (which == 1) {
    // ---- K: rows are compacted jc; batch known
    ushort* dst = kw + ((size_t)((batch << 4) + h) * 2048) * 64;
#pragma unroll
    for (int r = 0; r < 4; ++r) {
      const int s = m0 + g * 4 + r;
      ushort* rowp = dst + (size_t)s * 64;
#pragma unroll
      for (int cs = 0; cs < 4; ++cs)
        rowp[cs * 16 + lr] = hfbits(acc[cs][r]);
    }
  } else {
    // ---- Q: full M; pre-scale by log2(e)
#pragma unroll
    for (int r = 0; r < 4; ++r) {
      int m = m0 + g * 4 + r;
      int b = m >> 11, s = m & 2047;
      ushort* rowp = qw + ((size_t)((b << 4) + h) * 2048 + s) * 64;
#pragma unroll
      for (int cs = 0; cs < 4; ++cs)
        rowp[cs * 16 + lr] = hfbits(acc[cs][r] * 1.44269504088896f);
    }
  }
}

// ---------------------------------------------------------------------------
// Kernel 3: flash attention over COMPACTED keys (proven R6/R12/R13 body).
// ---------------------------------------------------------------------------
__global__ __launch_bounds__(512, 4) void k_attn(const ushort* __restrict__ qw,
                                                 const ushort* __restrict__ kw,
                                                 const ushort* __restrict__ vc,
                                                 const float* __restrict__ biasc,
                                                 const int* __restrict__ nkvs,
                                                 float* __restrict__ out) {
  __shared__ __align__(16) ushort sK[2][64][64];   // 16 KB (2 bufs)
  __shared__ __align__(16) ushort sV[2][64][64];   // 16 KB (2 bufs)

  const int t = threadIdx.x;
  const int lane = t & 63, w = t >> 6;             // w in 0..7
  const int g = lane >> 4, lr = lane & 15;

  // XCD-clustered decode: id%8 = XCD; 4 bh x 16 qblk per XCD.
  const int id = blockIdx.x;                        // 0..511
  const int j = id >> 3;
  const int bh = (id & 7) * 4 + (j >> 4);
  const int qblk = j & 15;
  const int b = bh >> 4, h = bh & 15;

  const int ntk = nkvs[2 + b];                      // padded survivor count

  const int qrow = qblk * 128 + w * 16 + lr;
  const ushort* qp = qw + ((size_t)bh * 2048 + qrow) * 64;
  const half8 qb0 = *reinterpret_cast<const half8*>(qp + g * 8);
  const half8 qb1 = *reinterpret_cast<const half8*>(qp + 32 + g * 8);

  const ushort* kbh = kw + (size_t)bh * 2048 * 64;
  const ushort* vbh = vc + (size_t)bh * 64 * 2048;
  const float* biasb = biasc + b * 2048;

  const int krbase = (lr >> 2) * 8 + (lr & 3);
  const int kswz = (((lr & 3) << 1) ^ (lr >> 2)) << 4;

  // staging: wave w stages chunk w (1 KB) of both K and V tiles.
  const int sr0 = w * 8 + (lane >> 3);
  const int scb = (lane & 7) << 4;
  const int swz0 = scb ^ ((((sr0 & 3) << 1) ^ ((sr0 >> 3) & 3)) << 4);

  auto stage = [&](int bufi, int jtn) {
    gl16(kbh + (size_t)(jtn + sr0) * 64 + (swz0 >> 1), &sK[bufi][0][0] + w * 512);
    gl16(vbh + (size_t)sr0 * 2048 + jtn + (swz0 >> 1), &sV[bufi][0][0] + w * 512);
  };

  const half8 vones = {(_Float16)1.f, (_Float16)1.f, (_Float16)1.f, (_Float16)1.f,
                       (_Float16)1.f, (_Float16)1.f, (_Float16)1.f, (_Float16)1.f};

  float m_run = -__builtin_inff();   // running max (log2 units) for q = lr
  f32x4 o[4] = {};                   // o[dn][r]: q = g*4+r, d = dn*16+lr
  f32x4 oden = {};                   // oden[r]: sum_k P[q=g*4+r][k]

  stage(0, 0);
  __syncthreads();                   // drains vmcnt(0): tile 0 landed
  int buf = 0;

  for (int jt = 0; jt < ntk; jt += 64) {
    if (jt + 64 < ntk) stage(buf ^ 1, jt + 64);

    f32x4 bias4[4];
#pragma unroll
    for (int jn = 0; jn < 4; ++jn) {
      const int koff = (jn & 1) * 4 + (jn >> 1) * 32;
      bias4[jn] = *reinterpret_cast<const f32x4*>(biasb + jt + koff + g * 8);
    }

    half8 vf0[4], vf1[4];
#pragma unroll
    for (int dn = 0; dn < 4; ++dn) {
      const int vr = dn * 16 + lr;
      const int vswz = ((((lr & 3) << 1) ^ ((2 * dn + (lr >> 3)) & 3)) << 4);
      const char* vrow = (const char*)&sV[buf][vr][0];
      vf0[dn] = *reinterpret_cast<const half8*>(vrow + ((16 * g) ^ vswz));
      vf1[dn] = *reinterpret_cast<const half8*>(vrow + ((64 + 16 * g) ^ vswz));
    }

    float st[4][4];
#pragma unroll
    for (int jn = 0; jn < 4; ++jn) {
      const int koff = (jn & 1) * 4 + (jn >> 1) * 32;
      const int kr = koff + krbase;
      const char* krow = (const char*)&sK[buf][kr][0];
      half8 ka0 = *reinterpret_cast<const half8*>(krow + ((16 * g) ^ kswz));
      half8 ka1 = *reinterpret_cast<const half8*>(krow + ((64 + 16 * g) ^ kswz));
      f32x4 s4 = bias4[jn];
      s4 = MFMA16(ka0, qb0, s4);
      s4 = MFMA16(ka1, qb1, s4);
#pragma unroll
      for (int r = 0; r < 4; ++r) st[jn][r] = s4[r];
    }

    float ma = fmaxf(fmaxf(st[0][0], st[0][1]), st[0][2]);
    ma = fmaxf(fmaxf(ma, st[0][3]), st[1][0]);
    ma = fmaxf(fmaxf(ma, st[1][1]), st[1][2]);
    ma = fmaxf(ma, st[1][3]);
    float mb2 = fmaxf(fmaxf(st[2][0], st[2][1]), st[2][2]);
    mb2 = fmaxf(fmaxf(mb2, st[2][3]), st[3][0]);
    mb2 = fmaxf(fmaxf(mb2, st[3][1]), st[3][2]);
    mb2 = fmaxf(mb2, st[3][3]);
    float tmax = fmaxf(ma, mb2);
    tmax = fmaxf(tmax, __shfl_xor(tmax, 16));
    tmax = fmaxf(tmax, __shfl_xor(tmax, 32));

    if (!__all(tmax <= m_run + 8.f)) {
      const float mnew = fmaxf(m_run, tmax);
      const float sc = __builtin_amdgcn_exp2f(m_run - mnew);  // exp2(-inf)=0
      const float s0 = __shfl(sc, g * 4 + 0);
      const float s1 = __shfl(sc, g * 4 + 1);
      const float s2 = __shfl(sc, g * 4 + 2);
      const float s3 = __shfl(sc, g * 4 + 3);
#pragma unroll
      for (int dn = 0; dn < 4; ++dn) {
        o[dn][0] *= s0; o[dn][1] *= s1; o[dn][2] *= s2; o[dn][3] *= s3;
      }
      oden[0] *= s0; oden[1] *= s1; oden[2] *= s2; oden[3] *= s3;
      m_run = mnew;
    }

    unsigned int pd[8];
#pragma unroll
    for (int jn = 0; jn < 4; ++jn) {
      float p0 = __builtin_amdgcn_exp2f(st[jn][0] - m_run);
      float p1 = __builtin_amdgcn_exp2f(st[jn][1] - m_run);
      float p2 = __builtin_amdgcn_exp2f(st[jn][2] - m_run);
      float p3 = __builtin_amdgcn_exp2f(st[jn][3] - m_run);
      pd[jn * 2 + 0] = __builtin_bit_cast(unsigned int, __builtin_amdgcn_cvt_pkrtz(p0, p1));
      pd[jn * 2 + 1] = __builtin_bit_cast(unsigned int, __builtin_amdgcn_cvt_pkrtz(p2, p3));
    }

    union { unsigned int u[4]; half8 h; } pa0u, pa1u;
    pa0u.u[0] = pd[0]; pa0u.u[1] = pd[1]; pa0u.u[2] = pd[2]; pa0u.u[3] = pd[3];
    pa1u.u[0] = pd[4]; pa1u.u[1] = pd[5]; pa1u.u[2] = pd[6]; pa1u.u[3] = pd[7];

    __builtin_amdgcn_s_setprio(1);
#pragma unroll
    for (int dn = 0; dn < 4; ++dn) {
      o[dn] = MFMA16(pa0u.h, vf0[dn], o[dn]);
      o[dn] = MFMA16(pa1u.h, vf1[dn], o[dn]);
    }
    oden = MFMA16(pa0u.h, vones, oden);
    oden = MFMA16(pa1u.h, vones, oden);
    __builtin_amdgcn_s_setprio(0);

    __syncthreads();
    buf ^= 1;
  }

  const float i0 = 1.f / oden[0];
  const float i1 = 1.f / oden[1];
  const float i2 = 1.f / oden[2];
  const float i3 = 1.f / oden[3];
  const int s0r = qblk * 128 + w * 16 + g * 4;
  float* ob = out + ((size_t)b * 2048 + s0r) * 1024 + h * 64;
#pragma unroll
  for (int dn = 0; dn < 4; ++dn) {
    ob[0 * 1024 + dn * 16 + lr] = o[dn][0] * i0;
    ob[1 * 1024 + dn * 16 + lr] = o[dn][1] * i1;
    ob[2 * 1024 + dn * 16 + lr] = o[dn][2] * i2;
    ob[3 * 1024 + dn * 16 + lr] = o[dn][3] * i3;
  }
}

// ---------------------------------------------------------------------------
extern "C" void kernel_launch(void* const* d_in, const int* in_sizes, int n_in,
                              void* d_out, int out_size, void* d_ws, size_t ws_size,
                              hipStream_t stream) {
  const float* x = (const float*)d_in[0];     // [2][2048][1024] f32
  const float* W = (const float*)d_in[1];     // [1024][3072] f32
  const int* mask = (const int*)d_in[2];      // [2][2048] i32
  float* out = (float*)d_out;                 // [2][2048][1024] f32
  char* ws = (char*)d_ws;

  ushort* wt = (ushort*)(ws);                                  // 6,291,456 B
  ushort* qw = (ushort*)(ws + 6291456);                        // 8,388,608 B
  ushort* kw = (ushort*)(ws + 6291456 + 8388608);              // 8,388,608 B
  ushort* xh = (ushort*)(ws + 6291456 + 2 * (size_t)8388608);  // 8,388,608 B
  ushort* vc = (ushort*)(ws + 6291456 + 3 * (size_t)8388608);  // 8,388,608 B
  char* tail = ws + 6291456 + 4 * (size_t)8388608;
  float* biasc = (float*)(tail);                               // 16,384 B
  int* cidx = (int*)(tail + 16384);                            // 16,384 B
  int* nkvs = (int*)(tail + 32768);                            // 16 B

  k_prep<<<dim3(2816), 256, 0, stream>>>(W, wt, x, xh, mask, biasc, cidx, nkvs);
  k_gemm<<<dim3(3072), 256, 0, stream>>>(xh, wt, qw, kw, vc, cidx, nkvs);
  k_attn<<<dim3(512), 512, 0, stream>>>(qw, kw, vc, biasc, nkvs, out);
}

// Round 17
// 72.517 us; speedup vs baseline: 1.0706x; 1.0706x over previous
//
#include <hip/hip_runtime.h>

typedef _Float16 half8 __attribute__((ext_vector_type(8)));
typedef float f32x4 __attribute__((ext_vector_type(4)));

#define MFMA16(a, b, c) __builtin_amdgcn_mfma_f32_16x16x32_f16((a), (b), (c), 0, 0, 0)

static __device__ __forceinline__ unsigned short hfbits(float f) {
  return __builtin_bit_cast(unsigned short, (_Float16)f);
}

// async global->LDS, 16B per lane; LDS dest = uniform base + lane*16
static __device__ __forceinline__ void gl16(const ushort* g, ushort* l) {
  __builtin_amdgcn_global_load_lds(
      (const __attribute__((address_space(1))) unsigned int*)g,
      (__attribute__((address_space(3))) unsigned int*)l, 16, 0, 0);
}

// ---------------------------------------------------------------------------
// Kernel 1 (merged prep): blocks [0,768): W f32 -> Wt fp16 transposed;
// blocks [768,2816): x f32 -> xh fp16.  Block 768 additionally runs a
// block-wide prefix scan of mask per batch, producing:
//   cidx[b][jc]   = j-index of the jc-th surviving key (pads -> 0)
//   biasc[b][jc]  = 0 for jc < nkv[b], -1e9 for pads (QK C-init masking)
//   nkvs[b]=nkv, nkvs[2+b]=ceil64(nkv)
// ---------------------------------------------------------------------------
__global__ __launch_bounds__(256) void k_prep(const float* __restrict__ W,
                                              ushort* __restrict__ wt,
                                              const float* __restrict__ x,
                                              ushort* __restrict__ xh,
                                              const int* __restrict__ mask,
                                              float* __restrict__ biasc,
                                              int* __restrict__ cidx,
                                              int* __restrict__ nkvs) {
  __shared__ ushort tile[64][72];
  __shared__ int scnt[256];
  const int id = blockIdx.x;
  const int t = threadIdx.x;

  if (id >= 768) {                       // ---- xh cast part
    const int pb = id - 768;
    const size_t p = ((size_t)pb * 256 + t) * 8;
    float4 a = *reinterpret_cast<const float4*>(x + p);
    float4 b = *reinterpret_cast<const float4*>(x + p + 4);
    union { ushort u[8]; uint4 v; } pk;
    pk.u[0] = hfbits(a.x); pk.u[1] = hfbits(a.y);
    pk.u[2] = hfbits(a.z); pk.u[3] = hfbits(a.w);
    pk.u[4] = hfbits(b.x); pk.u[5] = hfbits(b.y);
    pk.u[6] = hfbits(b.z); pk.u[7] = hfbits(b.w);
    *reinterpret_cast<uint4*>(xh + p) = pk.v;

    if (pb == 0) {                       // ---- key-compaction scan
      for (int b = 0; b < 2; ++b) {
        const int* mb = mask + b * 2048;
        int mloc[8];
        int c = 0;
#pragma unroll
        for (int k = 0; k < 8; ++k) {
          mloc[k] = mb[t * 8 + k];
          c += (mloc[k] != 0);
        }
        scnt[t] = c;
        __syncthreads();
        // inclusive Hillis-Steele scan over 256 counts
        for (int off = 1; off < 256; off <<= 1) {
          int v = scnt[t];
          int u = (t >= off) ? scnt[t - off] : 0;
          __syncthreads();
          scnt[t] = v + u;
          __syncthreads();
        }
        const int total = scnt[255];
        int p2 = scnt[t] - c;            // exclusive prefix
#pragma unroll
        for (int k = 0; k < 8; ++k)
          if (mloc[k]) cidx[b * 2048 + (p2++)] = t * 8 + k;
        __syncthreads();
        for (int jc = t; jc < 2048; jc += 256) {
          if (jc >= total) cidx[b * 2048 + jc] = 0;   // pad -> valid row 0
          biasc[b * 2048 + jc] = (jc < total) ? 0.f : -1e9f;
        }
        if (t == 0) {
          nkvs[b] = total;
          nkvs[2 + b] = ((total + 63) >> 6) << 6;
        }
        __syncthreads();
      }
    }
    return;
  }

  // ---- Wt transpose part
  const int n0 = (id % 48) * 64, k0 = (id / 48) * 64;
#pragma unroll
  for (int i = 0; i < 4; ++i) {
    int p = t + i * 256;
    int r = p >> 4, c = (p & 15) << 2;
    float4 v = *reinterpret_cast<const float4*>(&W[(size_t)(k0 + r) * 3072 + n0 + c]);
    ushort4 u;
    u.x = hfbits(v.x); u.y = hfbits(v.y); u.z = hfbits(v.z); u.w = hfbits(v.w);
    *reinterpret_cast<ushort4*>(&tile[r][c]) = u;
  }
  __syncthreads();
#pragma unroll
  for (int i = 0; i < 4; ++i) {
    int p = t + i * 256;
    int rn = p >> 4, ck = (p & 15) << 2;
    ushort4 u;
    u.x = tile[ck + 0][rn]; u.y = tile[ck + 1][rn];
    u.z = tile[ck + 2][rn]; u.w = tile[ck + 3][rn];
    *reinterpret_cast<ushort4*>(&wt[(size_t)(n0 + rn) * 1024 + k0 + ck]) = u;
  }
}

// ---------------------------------------------------------------------------
// Kernel 2: qkv GEMM, 128x64 tiles (one head per block) — the R15 optimum
// of the tile-size curve: R14 (128x128, 2 blk/CU) under-occupied, R16
// (64x64, 5 blk/CU) over-trafficked + bank-conflicted.  2-phase dbuf with
// counted vmcnt(6); XCD chunking; compacted KV rows with per-lane gl16
// gather; fused compacted K/V epilogues.
// ---------------------------------------------------------------------------
__global__ __launch_bounds__(256) void k_gemm(const ushort* __restrict__ xh,
                                              const ushort* __restrict__ wt,
                                              ushort* __restrict__ qw,
                                              ushort* __restrict__ kw,
                                              ushort* __restrict__ vc,
                                              const int* __restrict__ cidx,
                                              const int* __restrict__ nkvs) {
  __shared__ __align__(16) ushort sA[2][128 * 64];   // 32 KB (2 bufs)
  __shared__ __align__(16) ushort sB[2][64 * 64];    // 16 KB (2 bufs)
  const int t = threadIdx.x;
  const int lane = t & 63, w = t >> 6;
  const int g = lane >> 4, lr = lane & 15;

  const int id = blockIdx.x;
  int ncol0, batch = 0, mrow0 = 0;     // ncol0: global N col base (of 3072)
  int which, h;
  bool compact = false;
  if (id < 512) {
    // Q part, XCD-chunked: per XCD an 8bn x 8bm chunk
    const int xcd = id & 7, wi = id >> 3;        // wi 0..63
    const int bn = (xcd & 1) * 8 + (wi & 7);     // head 0..15
    mrow0 = ((xcd >> 1) * 8 + (wi >> 3)) * 128;  // bm 0..31
    ncol0 = bn * 64;
    which = 0; h = bn;
  } else {
    // KV part, XCD-chunked; bmc interleaved across XCDs for even early-exit
    const int kid = id - 512;                    // 0..1023
    const int xcd = kid & 7, wi = kid >> 3;      // wi 0..127
    const int col = (xcd & 1) * 16 + (wi & 15);  // 0..31
    const int bmc = (wi >> 4) * 4 + (xcd >> 1);  // 0..31
    const int mt0 = (nkvs[0] + 127) >> 7;
    const int mt1 = (nkvs[1] + 127) >> 7;
    if (bmc < mt0) { batch = 0; mrow0 = bmc * 128; }
    else if (bmc < mt0 + mt1) { batch = 1; mrow0 = (bmc - mt0) * 128; }
    else return;                        // no surviving rows here
    compact = true;
    ncol0 = 1024 + col * 64;
    which = (col < 16) ? 1 : 2;
    h = col & 15;
  }

  // ---- A staging: 16 chunks (1KB); wave w stages chunks 4w..4w+3.
  int soffA[4];
  const ushort* asrc[4];
#pragma unroll
  for (int i = 0; i < 4; ++i) {
    const int c = 4 * w + i;
    const int r = c * 8 + (lane >> 3);
    const int sl = (lane & 7) ^ (((r & 3) << 1) ^ ((r >> 3) & 3));
    soffA[i] = sl * 8;
    int arow;
    if (compact) arow = batch * 2048 + cidx[batch * 2048 + mrow0 + r];
    else arow = mrow0 + r;
    asrc[i] = xh + (size_t)arow * 1024 + soffA[i];
  }
  // ---- B staging: 8 chunks; wave w stages chunks 2w..2w+1.
  int brow[2], soffB[2];
#pragma unroll
  for (int i = 0; i < 2; ++i) {
    const int c = 2 * w + i;
    const int r = c * 8 + (lane >> 3);
    const int sl = (lane & 7) ^ (((r & 3) << 1) ^ ((r >> 3) & 3));
    brow[i] = r;
    soffB[i] = sl * 8;
  }

  // read-side swizzles
  int raswz[2], rbswz[4];
#pragma unroll
  for (int rs = 0; rs < 2; ++rs) {
    const int ra = w * 32 + rs * 16 + lr;
    raswz[rs] = ((((ra & 3) << 1) ^ ((ra >> 3) & 3)) << 4);
  }
#pragma unroll
  for (int cs = 0; cs < 4; ++cs) {
    const int rb = cs * 16 + lr;
    rbswz[cs] = ((((rb & 3) << 1) ^ ((rb >> 3) & 3)) << 4);
  }

  auto stage = [&](int bi, int kt) {
#pragma unroll
    for (int i = 0; i < 4; ++i)
      gl16(asrc[i] + kt, sA[bi] + (4 * w + i) * 512);
#pragma unroll
    for (int i = 0; i < 2; ++i)
      gl16(wt + (size_t)(ncol0 + brow[i]) * 1024 + kt + soffB[i],
           sB[bi] + (2 * w + i) * 512);
  };

  f32x4 acc[2][4] = {};

  stage(0, 0);
  for (int it = 0; it < 16; ++it) {
    if (it < 15) {
      stage((it + 1) & 1, (it + 1) * 64);
      asm volatile("s_waitcnt vmcnt(6)" ::: "memory");   // prev stage landed
    } else {
      asm volatile("s_waitcnt vmcnt(0)" ::: "memory");
    }
    __builtin_amdgcn_sched_barrier(0);
    __builtin_amdgcn_s_barrier();
    __builtin_amdgcn_sched_barrier(0);

    const int cb = it & 1;
#pragma unroll
    for (int ks = 0; ks < 64; ks += 32) {
      half8 af[2], bb[4];
#pragma unroll
      for (int rs = 0; rs < 2; ++rs) {
        const int ra = w * 32 + rs * 16 + lr;
        af[rs] = *reinterpret_cast<const half8*>(
            (const char*)sA[cb] + ra * 128 + ((16 * g + 2 * ks) ^ raswz[rs]));
      }
#pragma unroll
      for (int cs = 0; cs < 4; ++cs) {
        const int rb = cs * 16 + lr;
        bb[cs] = *reinterpret_cast<const half8*>(
            (const char*)sB[cb] + rb * 128 + ((16 * g + 2 * ks) ^ rbswz[cs]));
      }
#pragma unroll
      for (int rs = 0; rs < 2; ++rs)
#pragma unroll
        for (int cs = 0; cs < 4; ++cs)
          acc[rs][cs] = MFMA16(af[rs], bb[cs], acc[rs][cs]);
    }
    __builtin_amdgcn_sched_barrier(0);
    __builtin_amdgcn_s_barrier();      // readers done before buf overwrite
    __builtin_amdgcn_sched_barrier(0);
  }

  const int m0 = mrow0 + w * 32;        // wave's row base (Q: global, KV: jc)

  if (which == 2) {
    // ---- V: per-wave 32x64 LDS transpose -> vc[bh][d][jc] (compacted).
    // Own-wave 4KB quadrant in sA[0] (all waves past final barrier).
    ushort* q = sA[0] + w * 2048;       // 32 jc x 64 d, row n stride 32
#pragma unroll
    for (int rs = 0; rs < 2; ++rs)
#pragma unroll
      for (int r = 0; r < 4; ++r) {
        const int ml = rs * 16 + g * 4 + r;          // local jc 0..31
#pragma unroll
        for (int cs = 0; cs < 4; ++cs) {
          const int n = cs * 16 + lr;                // d 0..63
          q[n * 32 + ((((ml >> 3) ^ (n & 3)) << 3) | (ml & 7))] =
              hfbits(acc[rs][cs][r]);
        }
      }
    ushort* vbase = vc + ((size_t)((batch << 4) + h) * 64) * 2048 + m0;
#pragma unroll
    for (int j = 0; j < 4; ++j) {
      const int dl = j * 16 + (lane >> 2);           // d 0..63
      const int mg = lane & 3;                       // jc group of 8
      uint4 vv = *reinterpret_cast<const uint4*>(
          q + dl * 32 + ((mg ^ (dl & 3)) << 3));
      *reinterpret_cast<uint4*>(vbase + (size_t)dl * 2048 + mg * 8) = vv;
    }
  } else if (which == 1) {
    // ---- K: rows are compacted jc; batch known
    ushort* dst = kw + ((size_t)((batch << 4) + h) * 2048) * 64;
#pragma unroll
    for (int rs = 0; rs < 2; ++rs) {
#pragma unroll
      for (int r = 0; r < 4; ++r) {
        const int s = m0 + rs * 16 + g * 4 + r;
        ushort* rowp = dst + (size_t)s * 64;
#pragma unroll
        for (int cs = 0; cs < 4; ++cs)
          rowp[cs * 16 + lr] = hfbits(acc[rs][cs][r]);
      }
    }
  } else {
    // ---- Q: full M; pre-scale by log2(e)
#pragma unroll
    for (int rs = 0; rs < 2; ++rs) {
#pragma unroll
      for (int r = 0; r < 4; ++r) {
        int m = m0 + rs * 16 + g * 4 + r;
        int b = m >> 11, s = m & 2047;
        ushort* rowp = qw + ((size_t)((b << 4) + h) * 2048 + s) * 64;
#pragma unroll
        for (int cs = 0; cs < 4; ++cs)
          rowp[cs * 16 + lr] = hfbits(acc[rs][cs][r] * 1.44269504088896f);
      }
    }
  }
}

// ---------------------------------------------------------------------------
// Kernel 3: flash attention over COMPACTED keys (proven R6/R12/R13 body).
// ---------------------------------------------------------------------------
__global__ __launch_bounds__(512, 4) void k_attn(const ushort* __restrict__ qw,
                                                 const ushort* __restrict__ kw,
                                                 const ushort* __restrict__ vc,
                                                 const float* __restrict__ biasc,
                                                 const int* __restrict__ nkvs,
                                                 float* __restrict__ out) {
  __shared__ __align__(16) ushort sK[2][64][64];   // 16 KB (2 bufs)
  __shared__ __align__(16) ushort sV[2][64][64];   // 16 KB (2 bufs)

  const int t = threadIdx.x;
  const int lane = t & 63, w = t >> 6;             // w in 0..7
  const int g = lane >> 4, lr = lane & 15;

  // XCD-clustered decode: id%8 = XCD; 4 bh x 16 qblk per XCD.
  const int id = blockIdx.x;                        // 0..511
  const int j = id >> 3;
  const int bh = (id & 7) * 4 + (j >> 4);
  const int qblk = j & 15;
  const int b = bh >> 4, h = bh & 15;

  const int ntk = nkvs[2 + b];                      // padded survivor count

  const int qrow = qblk * 128 + w * 16 + lr;
  const ushort* qp = qw + ((size_t)bh * 2048 + qrow) * 64;
  const half8 qb0 = *reinterpret_cast<const half8*>(qp + g * 8);
  const half8 qb1 = *reinterpret_cast<const half8*>(qp + 32 + g * 8);

  const ushort* kbh = kw + (size_t)bh * 2048 * 64;
  const ushort* vbh = vc + (size_t)bh * 64 * 2048;
  const float* biasb = biasc + b * 2048;

  const int krbase = (lr >> 2) * 8 + (lr & 3);
  const int kswz = (((lr & 3) << 1) ^ (lr >> 2)) << 4;

  // staging: wave w stages chunk w (1 KB) of both K and V tiles.
  const int sr0 = w * 8 + (lane >> 3);
  const int scb = (lane & 7) << 4;
  const int swz0 = scb ^ ((((sr0 & 3) << 1) ^ ((sr0 >> 3) & 3)) << 4);

  auto stage = [&](int bufi, int jtn) {
    gl16(kbh + (size_t)(jtn + sr0) * 64 + (swz0 >> 1), &sK[bufi][0][0] + w * 512);
    gl16(vbh + (size_t)sr0 * 2048 + jtn + (swz0 >> 1), &sV[bufi][0][0] + w * 512);
  };

  const half8 vones = {(_Float16)1.f, (_Float16)1.f, (_Float16)1.f, (_Float16)1.f,
                       (_Float16)1.f, (_Float16)1.f, (_Float16)1.f, (_Float16)1.f};

  float m_run = -__builtin_inff();   // running max (log2 units) for q = lr
  f32x4 o[4] = {};                   // o[dn][r]: q = g*4+r, d = dn*16+lr
  f32x4 oden = {};                   // oden[r]: sum_k P[q=g*4+r][k]

  stage(0, 0);
  __syncthreads();                   // drains vmcnt(0): tile 0 landed
  int buf = 0;

  for (int jt = 0; jt < ntk; jt += 64) {
    if (jt + 64 < ntk) stage(buf ^ 1, jt + 64);

    f32x4 bias4[4];
#pragma unroll
    for (int jn = 0; jn < 4; ++jn) {
      const int koff = (jn & 1) * 4 + (jn >> 1) * 32;
      bias4[jn] = *reinterpret_cast<const f32x4*>(biasb + jt + koff + g * 8);
    }

    half8 vf0[4], vf1[4];
#pragma unroll
    for (int dn = 0; dn < 4; ++dn) {
      const int vr = dn * 16 + lr;
      const int vswz = ((((lr & 3) << 1) ^ ((2 * dn + (lr >> 3)) & 3)) << 4);
      const char* vrow = (const char*)&sV[buf][vr][0];
      vf0[dn] = *reinterpret_cast<const half8*>(vrow + ((16 * g) ^ vswz));
      vf1[dn] = *reinterpret_cast<const half8*>(vrow + ((64 + 16 * g) ^ vswz));
    }

    float st[4][4];
#pragma unroll
    for (int jn = 0; jn < 4; ++jn) {
      const int koff = (jn & 1) * 4 + (jn >> 1) * 32;
      const int kr = koff + krbase;
      const char* krow = (const char*)&sK[buf][kr][0];
      half8 ka0 = *reinterpret_cast<const half8*>(krow + ((16 * g) ^ kswz));
      half8 ka1 = *reinterpret_cast<const half8*>(krow + ((64 + 16 * g) ^ kswz));
      f32x4 s4 = bias4[jn];
      s4 = MFMA16(ka0, qb0, s4);
      s4 = MFMA16(ka1, qb1, s4);
#pragma unroll
      for (int r = 0; r < 4; ++r) st[jn][r] = s4[r];
    }

    float ma = fmaxf(fmaxf(st[0][0], st[0][1]), st[0][2]);
    ma = fmaxf(fmaxf(ma, st[0][3]), st[1][0]);
    ma = fmaxf(fmaxf(ma, st[1][1]), st[1][2]);
    ma = fmaxf(ma, st[1][3]);
    float mb2 = fmaxf(fmaxf(st[2][0], st[2][1]), st[2][2]);
    mb2 = fmaxf(fmaxf(mb2, st[2][3]), st[3][0]);
    mb2 = fmaxf(fmaxf(mb2, st[3][1]), st[3][2]);
    mb2 = fmaxf(mb2, st[3][3]);
    float tmax = fmaxf(ma, mb2);
    tmax = fmaxf(tmax, __shfl_xor(tmax, 16));
    tmax = fmaxf(tmax, __shfl_xor(tmax, 32));

    if (!__all(tmax <= m_run + 8.f)) {
      const float mnew = fmaxf(m_run, tmax);
      const float sc = __builtin_amdgcn_exp2f(m_run - mnew);  // exp2(-inf)=0
      const float s0 = __shfl(sc, g * 4 + 0);
      const float s1 = __shfl(sc, g * 4 + 1);
      const float s2 = __shfl(sc, g * 4 + 2);
      const float s3 = __shfl(sc, g * 4 + 3);
#pragma unroll
      for (int dn = 0; dn < 4; ++dn) {
        o[dn][0] *= s0; o[dn][1] *= s1; o[dn][2] *= s2; o[dn][3] *= s3;
      }
      oden[0] *= s0; oden[1] *= s1; oden[2] *= s2; oden[3] *= s3;
      m_run = mnew;
    }

    unsigned int pd[8];
#pragma unroll
    for (int jn = 0; jn < 4; ++jn) {
      float p0 = __builtin_amdgcn_exp2f(st[jn][0] - m_run);
      float p1 = __builtin_amdgcn_exp2f(st[jn][1] - m_run);
      float p2 = __builtin_amdgcn_exp2f(st[jn][2] - m_run);
      float p3 = __builtin_amdgcn_exp2f(st[jn][3] - m_run);
      pd[jn * 2 + 0] = __builtin_bit_cast(unsigned int, __builtin_amdgcn_cvt_pkrtz(p0, p1));
      pd[jn * 2 + 1] = __builtin_bit_cast(unsigned int, __builtin_amdgcn_cvt_pkrtz(p2, p3));
    }

    union { unsigned int u[4]; half8 h; } pa0u, pa1u;
    pa0u.u[0] = pd[0]; pa0u.u[1] = pd[1]; pa0u.u[2] = pd[2]; pa0u.u[3] = pd[3];
    pa1u.u[0] = pd[4]; pa1u.u[1] = pd[5]; pa1u.u[2] = pd[6]; pa1u.u[3] = pd[7];

    __builtin_amdgcn_s_setprio(1);
#pragma unroll
    for (int dn = 0; dn < 4; ++dn) {
      o[dn] = MFMA16(pa0u.h, vf0[dn], o[dn]);
      o[dn] = MFMA16(pa1u.h, vf1[dn], o[dn]);
    }
    oden = MFMA16(pa0u.h, vones, oden);
    oden = MFMA16(pa1u.h, vones, oden);
    __builtin_amdgcn_s_setprio(0);

    __syncthreads();
    buf ^= 1;
  }

  const float i0 = 1.f / oden[0];
  const float i1 = 1.f / oden[1];
  const float i2 = 1.f / oden[2];
  const float i3 = 1.f / oden[3];
  const int s0r = qblk * 128 + w * 16 + g * 4;
  float* ob = out + ((size_t)b * 2048 + s0r) * 1024 + h * 64;
#pragma unroll
  for (int dn = 0; dn < 4; ++dn) {
    ob[0 * 1024 + dn * 16 + lr] = o[dn][0] * i0;
    ob[1 * 1024 + dn * 16 + lr] = o[dn][1] * i1;
    ob[2 * 1024 + dn * 16 + lr] = o[dn][2] * i2;
    ob[3 * 1024 + dn * 16 + lr] = o[dn][3] * i3;
  }
}

// ---------------------------------------------------------------------------
extern "C" void kernel_launch(void* const* d_in, const int* in_sizes, int n_in,
                              void* d_out, int out_size, void* d_ws, size_t ws_size,
                              hipStream_t stream) {
  const float* x = (const float*)d_in[0];     // [2][2048][1024] f32
  const float* W = (const float*)d_in[1];     // [1024][3072] f32
  const int* mask = (const int*)d_in[2];      // [2][2048] i32
  float* out = (float*)d_out;                 // [2][2048][1024] f32
  char* ws = (char*)d_ws;

  ushort* wt = (ushort*)(ws);                                  // 6,291,456 B
  ushort* qw = (ushort*)(ws + 6291456);                        // 8,388,608 B
  ushort* kw = (ushort*)(ws + 6291456 + 8388608);              // 8,388,608 B
  ushort* xh = (ushort*)(ws + 6291456 + 2 * (size_t)8388608);  // 8,388,608 B
  ushort* vc = (ushort*)(ws + 6291456 + 3 * (size_t)8388608);  // 8,388,608 B
  char* tail = ws + 6291456 + 4 * (size_t)8388608;
  float* biasc = (float*)(tail);                               // 16,384 B
  int* cidx = (int*)(tail + 16384);                            // 16,384 B
  int* nkvs = (int*)(tail + 32768);                            // 16 B

  k_prep<<<dim3(2816), 256, 0, stream>>>(W, wt, x, xh, mask, biasc, cidx, nkvs);
  k_gemm<<<dim3(1536), 256, 0, stream>>>(xh, wt, qw, kw, vc, cidx, nkvs);
  k_attn<<<dim3(512), 512, 0, stream>>>(qw, kw, vc, biasc, nkvs, out);
}